// Round 1
// baseline (321.436 us; speedup 1.0000x reference)
//
#include <hip/hip_runtime.h>
#include <stdint.h>

typedef __attribute__((ext_vector_type(4))) float f32x4;
typedef __attribute__((ext_vector_type(8))) short short8;

__device__ __forceinline__ short f2bf(float f) {
    union { float f; unsigned u; } x; x.f = f;
    return (short)((x.u + 0x7fffu + ((x.u >> 16) & 1u)) >> 16);
}

#define MFMA16(a, b, c) __builtin_amdgcn_mfma_f32_16x16x32_bf16((a), (b), (c), 0, 0, 0)

__global__ __launch_bounds__(256) void cast_f32_bf16(const float* __restrict__ src,
                                                     short* __restrict__ dst, int n8) {
    int i = blockIdx.x * 256 + threadIdx.x;
    if (i >= n8) return;
    float4 a = ((const float4*)src)[i * 2];
    float4 b = ((const float4*)src)[i * 2 + 1];
    short8 o;
    o[0] = f2bf(a.x); o[1] = f2bf(a.y); o[2] = f2bf(a.z); o[3] = f2bf(a.w);
    o[4] = f2bf(b.x); o[5] = f2bf(b.y); o[6] = f2bf(b.z); o[7] = f2bf(b.w);
    ((short8*)dst)[i] = o;
}

// C[M,N] = A[M,K] * B[N,K]^T, bf16 inputs, fp32 accum.
template <int OUT_BF16>
__global__ __launch_bounds__(256) void gemm_bt(const short* __restrict__ A,
                                               const short* __restrict__ B,
                                               void* __restrict__ Cout,
                                               int M, int N, int K) {
    __shared__ short sA[128][40];
    __shared__ short sB[128][40];
    const int t = threadIdx.x;
    const int l = t & 63, w = t >> 6;
    const int lr = l & 15, lg = l >> 4;
    const int m0 = blockIdx.y * 128, n0 = blockIdx.x * 128;
    const int wm = (w >> 1) * 64, wn = (w & 1) * 64;
    const int sr = t >> 1, sc = (t & 1) * 16;
    const short* Ap = A + (size_t)(m0 + sr) * K + sc;
    const short* Bp = B + (size_t)(n0 + sr) * K + sc;
    f32x4 acc[4][4] = {};
    for (int k0 = 0; k0 < K; k0 += 32) {
        short8 av0 = *(const short8*)(Ap + k0);
        short8 av1 = *(const short8*)(Ap + k0 + 8);
        short8 bv0 = *(const short8*)(Bp + k0);
        short8 bv1 = *(const short8*)(Bp + k0 + 8);
        *(short8*)&sA[sr][sc] = av0;
        *(short8*)&sA[sr][sc + 8] = av1;
        *(short8*)&sB[sr][sc] = bv0;
        *(short8*)&sB[sr][sc + 8] = bv1;
        __syncthreads();
        short8 af[4], bfr[4];
        #pragma unroll
        for (int m = 0; m < 4; ++m) af[m] = *(const short8*)&sA[wm + m * 16 + lr][lg * 8];
        #pragma unroll
        for (int n = 0; n < 4; ++n) bfr[n] = *(const short8*)&sB[wn + n * 16 + lr][lg * 8];
        #pragma unroll
        for (int m = 0; m < 4; ++m)
            #pragma unroll
            for (int n = 0; n < 4; ++n)
                acc[m][n] = MFMA16(af[m], bfr[n], acc[m][n]);
        __syncthreads();
    }
    #pragma unroll
    for (int m = 0; m < 4; ++m)
        #pragma unroll
        for (int n = 0; n < 4; ++n)
            #pragma unroll
            for (int r = 0; r < 4; ++r) {
                int mm = m0 + wm + m * 16 + lg * 4 + r;
                int nn = n0 + wn + n * 16 + lr;
                if (OUT_BF16) ((short*)Cout)[(size_t)mm * N + nn] = f2bf(acc[m][n][r]);
                else ((float*)Cout)[(size_t)mm * N + nn] = acc[m][n][r];
            }
}

// V part of qkv [m, 2048 + h*64 + d] -> vt[bh][d][s]
__global__ __launch_bounds__(256) void transpose_v(const short* __restrict__ qkv,
                                                   short* __restrict__ vt) {
    __shared__ short T[64][72];
    const int t = threadIdx.x;
    const int s0 = blockIdx.x * 64, bh = blockIdx.y;
    const int b = bh >> 4, h = bh & 15;
    const int rl = t >> 2, cg = (t & 3) * 16;
    const short* src = qkv + (size_t)(b * 2048 + s0 + rl) * 3072 + 2048 + h * 64 + cg;
    *(short8*)&T[rl][cg] = *(const short8*)src;
    *(short8*)&T[rl][cg + 8] = *(const short8*)(src + 8);
    __syncthreads();
    short8 o0, o1;
    #pragma unroll
    for (int e = 0; e < 8; ++e) o0[e] = T[cg + e][rl];
    #pragma unroll
    for (int e = 0; e < 8; ++e) o1[e] = T[cg + 8 + e][rl];
    short* dst = vt + ((size_t)bh * 64 + rl) * 2048 + s0 + cg;
    *(short8*)dst = o0;
    *(short8*)(dst + 8) = o1;
}

// Flash attention: 4 waves/block, 16 q-rows/wave, 32 keys/iter.
__global__ __launch_bounds__(256) void attn_kernel(const short* __restrict__ qkv,
                                                   const short* __restrict__ vt,
                                                   const int* __restrict__ amask,
                                                   const float* __restrict__ rel_bias,
                                                   short* __restrict__ xout) {
    __shared__ short sK[32][72];
    __shared__ short sV[64][40];
    __shared__ short sP[4][16][40];
    __shared__ float rb[32];
    __shared__ int mk[32];
    const int t = threadIdx.x;
    const int l = t & 63, w = t >> 6;
    const int lr = l & 15, lg = l >> 4;
    const int qt = blockIdx.x, bh = blockIdx.y;
    const int b = bh >> 4, h = bh & 15;
    const int q0 = qt * 64 + w * 16;
    if (t < 32) rb[t] = rel_bias[t * 16 + h];
    short8 qf[2];
    #pragma unroll
    for (int ds = 0; ds < 2; ++ds)
        qf[ds] = *(const short8*)(qkv + (size_t)(b * 2048 + q0 + lr) * 3072 + h * 64 + ds * 32 + lg * 8);
    f32x4 o[4] = {};
    float mreg[4], lreg[4];
    #pragma unroll
    for (int r = 0; r < 4; ++r) { mreg[r] = -1e30f; lreg[r] = 0.f; }
    const int kr = t >> 3, kc = (t & 7) * 8;
    const int vr = t >> 2, vc = (t & 3) * 8;
    const short* kgp = qkv + 1024 + h * 64 + kc;
    const short* vgp = vt + ((size_t)bh * 64 + vr) * 2048 + vc;
    for (int kt = 0; kt < 2048; kt += 32) {
        *(short8*)&sK[kr][kc] = *(const short8*)(kgp + (size_t)(b * 2048 + kt + kr) * 3072);
        *(short8*)&sV[vr][vc] = *(const short8*)(vgp + kt);
        if (t < 32) mk[t] = amask[b * 2048 + kt + t];
        __syncthreads();
        f32x4 s[2];
        #pragma unroll
        for (int ct = 0; ct < 2; ++ct) {
            f32x4 z = {};
            #pragma unroll
            for (int ds = 0; ds < 2; ++ds) {
                short8 kf = *(const short8*)&sK[ct * 16 + lr][ds * 32 + lg * 8];
                z = MFMA16(qf[ds], kf, z);
            }
            s[ct] = z;
        }
        float pe[2][4], mx[4];
        #pragma unroll
        for (int r = 0; r < 4; ++r) {
            const int i = q0 + lg * 4 + r;
            float best = -1e30f;
            #pragma unroll
            for (int ct = 0; ct < 2; ++ct) {
                int j = kt + ct * 16 + lr;
                int d = j - i;
                int a = d < 0 ? -d : d;
                int fb = a < 8 ? a
                         : (a < 12 ? 8 : a < 16 ? 9 : a < 23 ? 10 : a < 32 ? 11
                            : a < 46 ? 12 : a < 64 ? 13 : a < 91 ? 14 : 15);
                int bk = (d > 0 ? 16 : 0) + fb;
                float sc = s[ct][r] + rb[bk];
                if (mk[ct * 16 + lr] == 0) sc = -3e38f;
                pe[ct][r] = sc;
                best = fmaxf(best, sc);
            }
            #pragma unroll
            for (int off = 1; off < 16; off <<= 1)
                best = fmaxf(best, __shfl_xor(best, off));
            mx[r] = best;
        }
        #pragma unroll
        for (int r = 0; r < 4; ++r) {
            float mnew = fmaxf(mreg[r], mx[r]);
            float alpha = __expf(mreg[r] - mnew);
            mreg[r] = mnew;
            float p0 = __expf(pe[0][r] - mnew);
            float p1 = __expf(pe[1][r] - mnew);
            float rs = p0 + p1;
            #pragma unroll
            for (int off = 1; off < 16; off <<= 1)
                rs += __shfl_xor(rs, off);
            lreg[r] = lreg[r] * alpha + rs;
            #pragma unroll
            for (int dt = 0; dt < 4; ++dt) o[dt][r] *= alpha;
            sP[w][lg * 4 + r][lr] = f2bf(p0);
            sP[w][lg * 4 + r][16 + lr] = f2bf(p1);
        }
        __syncthreads();
        short8 pf = *(const short8*)&sP[w][lr][lg * 8];
        #pragma unroll
        for (int dt = 0; dt < 4; ++dt) {
            short8 vf = *(const short8*)&sV[dt * 16 + lr][lg * 8];
            o[dt] = MFMA16(pf, vf, o[dt]);
        }
        __syncthreads();
    }
    #pragma unroll
    for (int r = 0; r < 4; ++r) {
        float inv = 1.0f / lreg[r];
        #pragma unroll
        for (int dt = 0; dt < 4; ++dt)
            xout[(size_t)(b * 2048 + q0 + lg * 4 + r) * 1024 + h * 64 + dt * 16 + lr] =
                f2bf(o[dt][r] * inv);
    }
}

extern "C" void kernel_launch(void* const* d_in, const int* in_sizes, int n_in,
                              void* d_out, int out_size, void* d_ws, size_t ws_size,
                              hipStream_t stream) {
    const float* hidden = (const float*)d_in[0];
    const int* amask = (const int*)d_in[1];
    const float* w_qkv = (const float*)d_in[2];
    const float* rel_bias = (const float*)d_in[3];
    const float* w_o = (const float*)d_in[4];
    if (ws_size < 58720256) return;  // need 56 MB of scratch
    char* ws = (char*)d_ws;
    short* hidden_bf = (short*)(ws + 0);         //  8.0 MB: [4096,1024] bf16
    short* wqkv_bf   = (short*)(ws + 8388608);   //  6.0 MB: [3072,1024] bf16
    short* wo_bf     = (short*)(ws + 14680064);  //  2.0 MB: [1024,1024] bf16
    short* qkv       = (short*)(ws + 16777216);  // 24.0 MB: [4096,3072] bf16
    short* vt        = (short*)(ws + 41943040);  //  8.0 MB: [32,64,2048] bf16
    short* xbuf      = (short*)(ws + 50331648);  //  8.0 MB: [4096,1024] bf16

    cast_f32_bf16<<<2048, 256, 0, stream>>>(hidden, hidden_bf, 524288);
    cast_f32_bf16<<<1536, 256, 0, stream>>>(w_qkv, wqkv_bf, 393216);
    cast_f32_bf16<<<512, 256, 0, stream>>>(w_o, wo_bf, 131072);
    gemm_bt<1><<<dim3(24, 32), 256, 0, stream>>>(hidden_bf, wqkv_bf, qkv, 4096, 3072, 1024);
    transpose_v<<<dim3(32, 32), 256, 0, stream>>>(qkv, vt);
    attn_kernel<<<dim3(32, 32), 256, 0, stream>>>(qkv, vt, amask, rel_bias, xbuf);
    gemm_bt<0><<<dim3(8, 32), 256, 0, stream>>>(xbuf, wo_bf, d_out, 4096, 1024, 1024);
}

// Round 2
// 227.428 us; speedup vs baseline: 1.4133x; 1.4133x over previous
//
#include <hip/hip_runtime.h>
#include <stdint.h>

typedef __attribute__((ext_vector_type(4))) float f32x4;
typedef __attribute__((ext_vector_type(8))) short short8;

__device__ __forceinline__ short f2bf(float f) {
    union { float f; unsigned u; } x; x.f = f;
    return (short)((x.u + 0x7fffu + ((x.u >> 16) & 1u)) >> 16);
}

#define MFMA16(a, b, c) __builtin_amdgcn_mfma_f32_16x16x32_bf16((a), (b), (c), 0, 0, 0)

__device__ __forceinline__ void gload16(const void* g, void* l) {
    __builtin_amdgcn_global_load_lds((const __attribute__((address_space(1))) void*)g,
                                     (__attribute__((address_space(3))) void*)l, 16, 0, 0);
}

__global__ __launch_bounds__(256) void cast_f32_bf16(const float* __restrict__ src,
                                                     short* __restrict__ dst, int n8) {
    int i = blockIdx.x * 256 + threadIdx.x;
    if (i >= n8) return;
    float4 a = ((const float4*)src)[i * 2];
    float4 b = ((const float4*)src)[i * 2 + 1];
    short8 o;
    o[0] = f2bf(a.x); o[1] = f2bf(a.y); o[2] = f2bf(a.z); o[3] = f2bf(a.w);
    o[4] = f2bf(b.x); o[5] = f2bf(b.y); o[6] = f2bf(b.z); o[7] = f2bf(b.w);
    ((short8*)dst)[i] = o;
}

// C[M,N] = A[M,K] * B[N,K]^T, bf16 in, fp32 accum. m97 structure: linear LDS +
// global_load_lds width-16 staging, BK=32, 128x128 tile, 4 waves.
template <int OUT_BF16>
__global__ __launch_bounds__(256) void gemm_bt(const short* __restrict__ A,
                                               const short* __restrict__ B,
                                               void* __restrict__ Cout,
                                               int M, int N, int K) {
    __shared__ short sA[4096];
    __shared__ short sB[4096];
    const int t = threadIdx.x;
    const int l = t & 63, w = t >> 6;
    const int lr = l & 15, lg = l >> 4;
    const int m0 = blockIdx.y * 128, n0 = blockIdx.x * 128;
    const int wm = (w >> 1) * 64, wn = (w & 1) * 64;
    const int c0 = w * 64 + l, c1 = c0 + 256;  // 16B chunk ids (row=c>>2, k=(c&3)*8)
    const short* Ap0 = A + (size_t)(m0 + (c0 >> 2)) * K + (c0 & 3) * 8;
    const short* Ap1 = A + (size_t)(m0 + (c1 >> 2)) * K + (c1 & 3) * 8;
    const short* Bp0 = B + (size_t)(n0 + (c0 >> 2)) * K + (c0 & 3) * 8;
    const short* Bp1 = B + (size_t)(n0 + (c1 >> 2)) * K + (c1 & 3) * 8;
    short* lA0 = sA + w * 512;
    short* lA1 = sA + 2048 + w * 512;
    short* lB0 = sB + w * 512;
    short* lB1 = sB + 2048 + w * 512;
    f32x4 acc[4][4] = {};
    for (int k0 = 0; k0 < K; k0 += 32) {
        gload16(Ap0 + k0, lA0);
        gload16(Ap1 + k0, lA1);
        gload16(Bp0 + k0, lB0);
        gload16(Bp1 + k0, lB1);
        __syncthreads();
        short8 af[4], bfr[4];
        #pragma unroll
        for (int m = 0; m < 4; ++m) af[m] = *(const short8*)&sA[(wm + m * 16 + lr) * 32 + lg * 8];
        #pragma unroll
        for (int n = 0; n < 4; ++n) bfr[n] = *(const short8*)&sB[(wn + n * 16 + lr) * 32 + lg * 8];
        #pragma unroll
        for (int m = 0; m < 4; ++m)
            #pragma unroll
            for (int n = 0; n < 4; ++n)
                acc[m][n] = MFMA16(af[m], bfr[n], acc[m][n]);
        __syncthreads();
    }
    #pragma unroll
    for (int m = 0; m < 4; ++m)
        #pragma unroll
        for (int n = 0; n < 4; ++n)
            #pragma unroll
            for (int r = 0; r < 4; ++r) {
                int mm = m0 + wm + m * 16 + lg * 4 + r;
                int nn = n0 + wn + n * 16 + lr;
                if (OUT_BF16) ((short*)Cout)[(size_t)mm * N + nn] = f2bf(acc[m][n][r]);
                else ((float*)Cout)[(size_t)mm * N + nn] = acc[m][n][r];
            }
}

// V part of qkv [m, 2048 + h*64 + d] -> vt[bh][d][s]
__global__ __launch_bounds__(256) void transpose_v(const short* __restrict__ qkv,
                                                   short* __restrict__ vt) {
    __shared__ short T[64][72];
    const int t = threadIdx.x;
    const int s0 = blockIdx.x * 64, bh = blockIdx.y;
    const int b = bh >> 4, h = bh & 15;
    const int rl = t >> 2, cg = (t & 3) * 16;
    const short* src = qkv + (size_t)(b * 2048 + s0 + rl) * 3072 + 2048 + h * 64 + cg;
    *(short8*)&T[rl][cg] = *(const short8*)src;
    *(short8*)&T[rl][cg + 8] = *(const short8*)(src + 8);
    __syncthreads();
    short8 o0, o1;
    #pragma unroll
    for (int e = 0; e < 8; ++e) o0[e] = T[cg + e][rl];
    #pragma unroll
    for (int e = 0; e < 8; ++e) o1[e] = T[cg + 8 + e][rl];
    short* dst = vt + ((size_t)bh * 64 + rl) * 2048 + s0 + cg;
    *(short8*)dst = o0;
    *(short8*)(dst + 8) = o1;
}

// Flash attention: 4 waves/block, 16 q-rows/wave, KVBLK=64.
// Bias via LDS LUT; defer-max rescale skip; register-prefetched staging.
__global__ __launch_bounds__(256) void attn_kernel(const short* __restrict__ qkv,
                                                   const short* __restrict__ vt,
                                                   const int* __restrict__ amask,
                                                   const float* __restrict__ rel_bias,
                                                   short* __restrict__ xout) {
    __shared__ float tbl[4096];     // bias LUT: tbl[j - i + 2047]
    __shared__ short sK[64][72];    // [key][d]
    __shared__ short sV[64][72];    // [d][key]  (V^T)
    __shared__ short sP[4][16][72]; // per-wave P: [q-local][key]
    const int t = threadIdx.x;
    const int l = t & 63, w = t >> 6;
    const int lr = l & 15, lg = l >> 4;
    const int qt = blockIdx.x, bh = blockIdx.y;
    const int b = bh >> 4, h = bh & 15;
    const int q0 = qt * 64 + w * 16;

    // build bias LUT (integer-exact bucket thresholds, verified round 1)
    for (int idx = t; idx < 4095; idx += 256) {
        int d = idx - 2047;
        int a = d < 0 ? -d : d;
        int fb = a < 8 ? a
                 : (a < 12 ? 8 : a < 16 ? 9 : a < 23 ? 10 : a < 32 ? 11
                    : a < 46 ? 12 : a < 64 ? 13 : a < 91 ? 14 : 15);
        int bk = (d > 0 ? 16 : 0) + fb;
        tbl[idx] = rel_bias[bk * 16 + h];
    }

    short8 qf[2];
    #pragma unroll
    for (int ds = 0; ds < 2; ++ds)
        qf[ds] = *(const short8*)(qkv + (size_t)(b * 2048 + q0 + lr) * 3072 + h * 64 + ds * 32 + lg * 8);

    f32x4 o[4] = {};
    float mreg[4], lreg[4];
    #pragma unroll
    for (int r = 0; r < 4; ++r) { mreg[r] = -1e30f; lreg[r] = 0.f; }

    // staging: 64 rows x 64 cols per tile, 16 elems/thread
    const int srow = t >> 2, scol = (t & 3) * 16;
    const short* kgp = qkv + (size_t)(b * 2048 + srow) * 3072 + 1024 + h * 64 + scol;
    const short* vgp = vt + ((size_t)bh * 64 + srow) * 2048 + scol;
    const int* mgp = amask + b * 2048 + lr;

    short8 stg[4];
    int mk[4], mkn[4];
    stg[0] = *(const short8*)kgp;
    stg[1] = *(const short8*)(kgp + 8);
    stg[2] = *(const short8*)vgp;
    stg[3] = *(const short8*)(vgp + 8);
    #pragma unroll
    for (int ct = 0; ct < 4; ++ct) mk[ct] = mgp[ct * 16];

    for (int kt = 0; kt < 2048; kt += 64) {
        *(short8*)&sK[srow][scol] = stg[0];
        *(short8*)&sK[srow][scol + 8] = stg[1];
        *(short8*)&sV[srow][scol] = stg[2];
        *(short8*)&sV[srow][scol + 8] = stg[3];
        __syncthreads();
        if (kt + 64 < 2048) {  // prefetch next tile into registers (latency hides under compute)
            const short* kp = kgp + (size_t)(kt + 64) * 3072;
            stg[0] = *(const short8*)kp;
            stg[1] = *(const short8*)(kp + 8);
            stg[2] = *(const short8*)(vgp + kt + 64);
            stg[3] = *(const short8*)(vgp + kt + 72);
            #pragma unroll
            for (int ct = 0; ct < 4; ++ct) mkn[ct] = mgp[kt + 64 + ct * 16];
        }
        // QK^T
        f32x4 s[4];
        #pragma unroll
        for (int ct = 0; ct < 4; ++ct) {
            f32x4 z = {};
            #pragma unroll
            for (int ds = 0; ds < 2; ++ds) {
                short8 kf = *(const short8*)&sK[ct * 16 + lr][ds * 32 + lg * 8];
                z = MFMA16(qf[ds], kf, z);
            }
            s[ct] = z;
        }
        // bias + mask + row max
        float pe[4][4], pmax[4];
        #pragma unroll
        for (int r = 0; r < 4; ++r) pmax[r] = -3e38f;
        const int ibase = kt + lr - q0 - lg * 4 + 2047;
        #pragma unroll
        for (int ct = 0; ct < 4; ++ct) {
            float pen = mk[ct] ? 0.f : -3e38f;
            #pragma unroll
            for (int r = 0; r < 4; ++r) {
                float sc = s[ct][r] + tbl[ibase + ct * 16 - r] + pen;
                pe[ct][r] = sc;
                pmax[r] = fmaxf(pmax[r], sc);
            }
        }
        #pragma unroll
        for (int r = 0; r < 4; ++r)
            #pragma unroll
            for (int off = 1; off < 16; off <<= 1)
                pmax[r] = fmaxf(pmax[r], __shfl_xor(pmax[r], off));
        // defer-max: only rescale when a row max grew by > 8
        bool need = (pmax[0] > mreg[0] + 8.f) | (pmax[1] > mreg[1] + 8.f) |
                    (pmax[2] > mreg[2] + 8.f) | (pmax[3] > mreg[3] + 8.f);
        if (__any(need)) {
            #pragma unroll
            for (int r = 0; r < 4; ++r) {
                float mnew = fmaxf(mreg[r], pmax[r]);
                float a2 = __expf(mreg[r] - mnew);
                mreg[r] = mnew;
                lreg[r] *= a2;
                #pragma unroll
                for (int dt = 0; dt < 4; ++dt) o[dt][r] *= a2;
            }
        }
        // p = exp(s - m), write P (same-wave LDS, no barrier), accumulate l
        #pragma unroll
        for (int r = 0; r < 4; ++r) {
            float rs = 0.f;
            #pragma unroll
            for (int ct = 0; ct < 4; ++ct) {
                float p = __expf(pe[ct][r] - mreg[r]);
                rs += p;
                sP[w][lg * 4 + r][ct * 16 + lr] = f2bf(p);
            }
            #pragma unroll
            for (int off = 1; off < 16; off <<= 1) rs += __shfl_xor(rs, off);
            lreg[r] += rs;
        }
        // PV
        #pragma unroll
        for (int kk = 0; kk < 2; ++kk) {
            short8 pf = *(const short8*)&sP[w][lr][kk * 32 + lg * 8];
            #pragma unroll
            for (int dt = 0; dt < 4; ++dt) {
                short8 vf = *(const short8*)&sV[dt * 16 + lr][kk * 32 + lg * 8];
                o[dt] = MFMA16(pf, vf, o[dt]);
            }
        }
        __syncthreads();
        #pragma unroll
        for (int ct = 0; ct < 4; ++ct) mk[ct] = mkn[ct];
    }
    #pragma unroll
    for (int r = 0; r < 4; ++r) {
        float inv = 1.0f / lreg[r];
        #pragma unroll
        for (int dt = 0; dt < 4; ++dt)
            xout[(size_t)(b * 2048 + q0 + lg * 4 + r) * 1024 + h * 64 + dt * 16 + lr] =
                f2bf(o[dt][r] * inv);
    }
}

extern "C" void kernel_launch(void* const* d_in, const int* in_sizes, int n_in,
                              void* d_out, int out_size, void* d_ws, size_t ws_size,
                              hipStream_t stream) {
    const float* hidden = (const float*)d_in[0];
    const int* amask = (const int*)d_in[1];
    const float* w_qkv = (const float*)d_in[2];
    const float* rel_bias = (const float*)d_in[3];
    const float* w_o = (const float*)d_in[4];
    if (ws_size < 58720256) return;  // need 56 MB of scratch
    char* ws = (char*)d_ws;
    short* hidden_bf = (short*)(ws + 0);         //  8.0 MB
    short* wqkv_bf   = (short*)(ws + 8388608);   //  6.0 MB
    short* wo_bf     = (short*)(ws + 14680064);  //  2.0 MB
    short* qkv       = (short*)(ws + 16777216);  // 24.0 MB
    short* vt        = (short*)(ws + 41943040);  //  8.0 MB
    short* xbuf      = (short*)(ws + 50331648);  //  8.0 MB

    cast_f32_bf16<<<2048, 256, 0, stream>>>(hidden, hidden_bf, 524288);
    cast_f32_bf16<<<1536, 256, 0, stream>>>(w_qkv, wqkv_bf, 393216);
    cast_f32_bf16<<<512, 256, 0, stream>>>(w_o, wo_bf, 131072);
    gemm_bt<1><<<dim3(24, 32), 256, 0, stream>>>(hidden_bf, wqkv_bf, qkv, 4096, 3072, 1024);
    transpose_v<<<dim3(32, 32), 256, 0, stream>>>(qkv, vt);
    attn_kernel<<<dim3(32, 32), 256, 0, stream>>>(qkv, vt, amask, rel_bias, xbuf);
    gemm_bt<0><<<dim3(8, 32), 256, 0, stream>>>(xbuf, wo_bf, d_out, 4096, 1024, 1024);
}

// Round 3
// 155.591 us; speedup vs baseline: 2.0659x; 1.4617x over previous
//
#include <hip/hip_runtime.h>
#include <stdint.h>

typedef __attribute__((ext_vector_type(4))) float f32x4;
typedef __attribute__((ext_vector_type(8))) short short8;
typedef __attribute__((ext_vector_type(4))) short short4v;
typedef __attribute__((ext_vector_type(2))) unsigned uint2v;

__device__ __forceinline__ short f2bf(float f) {
    union { float f; unsigned u; } x; x.f = f;
    return (short)((x.u + 0x7fffu + ((x.u >> 16) & 1u)) >> 16);
}

__device__ __forceinline__ unsigned cvt_pk_bf16(float lo, float hi) {
    unsigned r;
    asm("v_cvt_pk_bf16_f32 %0, %1, %2" : "=v"(r) : "v"(lo), "v"(hi));
    return r;
}

#define MFMA16(a, b, c) __builtin_amdgcn_mfma_f32_16x16x32_bf16((a), (b), (c), 0, 0, 0)

__device__ __forceinline__ void gload16(const void* g, void* l) {
    __builtin_amdgcn_global_load_lds((const __attribute__((address_space(1))) void*)g,
                                     (__attribute__((address_space(3))) void*)l, 16, 0, 0);
}

__global__ __launch_bounds__(256) void cast_f32_bf16(const float* __restrict__ src,
                                                     short* __restrict__ dst, int n8) {
    int i = blockIdx.x * 256 + threadIdx.x;
    if (i >= n8) return;
    float4 a = ((const float4*)src)[i * 2];
    float4 b = ((const float4*)src)[i * 2 + 1];
    short8 o;
    o[0] = f2bf(a.x); o[1] = f2bf(a.y); o[2] = f2bf(a.z); o[3] = f2bf(a.w);
    o[4] = f2bf(b.x); o[5] = f2bf(b.y); o[6] = f2bf(b.z); o[7] = f2bf(b.w);
    ((short8*)dst)[i] = o;
}

// C[M,N] = A[M,K] * B[N,K]^T, bf16 in, fp32 accum (m97 structure).
template <int OUT_BF16>
__global__ __launch_bounds__(256) void gemm_bt(const short* __restrict__ A,
                                               const short* __restrict__ B,
                                               void* __restrict__ Cout,
                                               int M, int N, int K) {
    __shared__ short sA[4096];
    __shared__ short sB[4096];
    const int t = threadIdx.x;
    const int l = t & 63, w = t >> 6;
    const int lr = l & 15, lg = l >> 4;
    const int m0 = blockIdx.y * 128, n0 = blockIdx.x * 128;
    const int wm = (w >> 1) * 64, wn = (w & 1) * 64;
    const int c0 = w * 64 + l, c1 = c0 + 256;
    const short* Ap0 = A + (size_t)(m0 + (c0 >> 2)) * K + (c0 & 3) * 8;
    const short* Ap1 = A + (size_t)(m0 + (c1 >> 2)) * K + (c1 & 3) * 8;
    const short* Bp0 = B + (size_t)(n0 + (c0 >> 2)) * K + (c0 & 3) * 8;
    const short* Bp1 = B + (size_t)(n0 + (c1 >> 2)) * K + (c1 & 3) * 8;
    short* lA0 = sA + w * 512;
    short* lA1 = sA + 2048 + w * 512;
    short* lB0 = sB + w * 512;
    short* lB1 = sB + 2048 + w * 512;
    f32x4 acc[4][4] = {};
    for (int k0 = 0; k0 < K; k0 += 32) {
        gload16(Ap0 + k0, lA0);
        gload16(Ap1 + k0, lA1);
        gload16(Bp0 + k0, lB0);
        gload16(Bp1 + k0, lB1);
        __syncthreads();
        short8 af[4], bfr[4];
        #pragma unroll
        for (int m = 0; m < 4; ++m) af[m] = *(const short8*)&sA[(wm + m * 16 + lr) * 32 + lg * 8];
        #pragma unroll
        for (int n = 0; n < 4; ++n) bfr[n] = *(const short8*)&sB[(wn + n * 16 + lr) * 32 + lg * 8];
        #pragma unroll
        for (int m = 0; m < 4; ++m)
            #pragma unroll
            for (int n = 0; n < 4; ++n)
                acc[m][n] = MFMA16(af[m], bfr[n], acc[m][n]);
        __syncthreads();
    }
    #pragma unroll
    for (int m = 0; m < 4; ++m)
        #pragma unroll
        for (int n = 0; n < 4; ++n)
            #pragma unroll
            for (int r = 0; r < 4; ++r) {
                int mm = m0 + wm + m * 16 + lg * 4 + r;
                int nn = n0 + wn + n * 16 + lr;
                if (OUT_BF16) ((short*)Cout)[(size_t)mm * N + nn] = f2bf(acc[m][n][r]);
                else ((float*)Cout)[(size_t)mm * N + nn] = acc[m][n][r];
            }
}

// V part of qkv [m, 2048 + h*64 + d] -> vt[bh][d][s]
__global__ __launch_bounds__(256) void transpose_v(const short* __restrict__ qkv,
                                                   short* __restrict__ vt) {
    __shared__ short T[64][72];
    const int t = threadIdx.x;
    const int s0 = blockIdx.x * 64, bh = blockIdx.y;
    const int b = bh >> 4, h = bh & 15;
    const int rl = t >> 2, cg = (t & 3) * 16;
    const short* src = qkv + (size_t)(b * 2048 + s0 + rl) * 3072 + 2048 + h * 64 + cg;
    *(short8*)&T[rl][cg] = *(const short8*)src;
    *(short8*)&T[rl][cg + 8] = *(const short8*)(src + 8);
    __syncthreads();
    short8 o0, o1;
    #pragma unroll
    for (int e = 0; e < 8; ++e) o0[e] = T[cg + e][rl];
    #pragma unroll
    for (int e = 0; e < 8; ++e) o1[e] = T[cg + 8 + e][rl];
    short* dst = vt + ((size_t)bh * 64 + rl) * 2048 + s0 + cg;
    *(short8*)dst = o0;
    *(short8*)(dst + 8) = o1;
}

// Flash attention, swapped-QK^T (scores lane-local per q-row).
// 4 waves x 16 q-rows, KVBLK=64. Flat-bias fast path off-diagonal.
__global__ __launch_bounds__(256, 4) void attn_kernel(const short* __restrict__ qkv,
                                                      const short* __restrict__ vt,
                                                      const int* __restrict__ amask,
                                                      const float* __restrict__ rel_bias,
                                                      short* __restrict__ xout) {
    __shared__ float tbl[2176];      // bias window: idx = (j - i) + q0b + 63, range [0,2110]
    __shared__ short sK[4096];       // [key 64][dk 64], XOR-swizzled 16B chunks
    __shared__ short sV[4096];       // [d 64][key 64], XOR-swizzled 16B chunks
    __shared__ short sP[4][16][72];  // per-wave P^T: [q-local][key]
    const int t = threadIdx.x;
    const int l = t & 63, w = t >> 6;
    const int lr = l & 15, lg = l >> 4;
    const int qt = blockIdx.x, bh = blockIdx.y;
    const int b = bh >> 4, h = bh & 15;
    const int q0b = qt * 64;
    const int q0 = q0b + w * 16;

    // bias LUT over this block's (j-i) window (integer-exact buckets)
    for (int idx = t; idx < 2111; idx += 256) {
        int d = idx - q0b - 63;
        int a = d < 0 ? -d : d;
        int fb = a < 8 ? a
                 : (a < 12 ? 8 : a < 16 ? 9 : a < 23 ? 10 : a < 32 ? 11
                    : a < 46 ? 12 : a < 64 ? 13 : a < 91 ? 14 : 15);
        int bk = (d > 0 ? 16 : 0) + fb;
        tbl[idx] = rel_bias[bk * 16 + h];
    }
    const float rbp = rel_bias[31 * 16 + h];  // d >= 91
    const float rbn = rel_bias[15 * 16 + h];  // d <= -91

    // Q fragment (B-operand): col=lr=q-local, k = ds*32 + lg*8 + j
    short8 qf[2];
    #pragma unroll
    for (int ds = 0; ds < 2; ++ds)
        qf[ds] = *(const short8*)(qkv + (size_t)(b * 2048 + q0 + lr) * 3072 + h * 64 + ds * 32 + lg * 8);

    f32x4 o[4] = {};
    float mreg = -1e30f, lreg = 0.f;

    // staging addresses: chunk c = {t, t+256}; row = c>>3, src chunk = (c&7)^(row&7)
    const int srow = t >> 3;
    const int scp = ((t & 7) ^ (srow & 7)) * 8;
    const short* kgp = qkv + (size_t)(b * 2048 + srow) * 3072 + 1024 + h * 64 + scp;
    const short* kgp2 = kgp + (size_t)32 * 3072;
    const short* vgp = vt + ((size_t)bh * 64 + srow) * 2048 + scp;
    const short* vgp2 = vgp + (size_t)32 * 2048;
    short* ldsK = sK + w * 512;
    short* ldsV = sV + w * 512;
    const int4* mp = (const int4*)(amask + b * 2048);
    const int sw8 = (lr & 7) * 8;
    const int ibb = -w * 16 + lg * 4 - lr + 63;

    for (int kt = 0; kt < 2048; kt += 64) {
        gload16(kgp + (size_t)kt * 3072, ldsK);
        gload16(kgp2 + (size_t)kt * 3072, ldsK + 2048);
        gload16(vgp + kt, ldsV);
        gload16(vgp2 + kt, ldsV + 2048);
        int4 cm[4];
        #pragma unroll
        for (int ct = 0; ct < 4; ++ct) cm[ct] = mp[(kt >> 2) + ct * 4 + lg];
        __syncthreads();

        // S^T = K * Q^T : lane holds q = q0+lr, keys kt + ct*16 + lg*4 + r
        f32x4 pe[4];
        #pragma unroll
        for (int ct = 0; ct < 4; ++ct) {
            f32x4 z = {};
            #pragma unroll
            for (int ds = 0; ds < 2; ++ds) {
                short8 kf = *(const short8*)&sK[(ct * 16 + lr) * 64 + ((ds * 32 + lg * 8) ^ sw8)];
                z = MFMA16(kf, qf[ds], z);
            }
            pe[ct] = z;
        }

        // bias
        float cb;
        if (kt >= q0 + 106) {
            cb = rbp;
        } else if (kt + 63 <= q0 - 91) {
            cb = rbn;
        } else {
            cb = 0.f;
            const int ib = kt + ibb;
            #pragma unroll
            for (int ct = 0; ct < 4; ++ct)
                #pragma unroll
                for (int r = 0; r < 4; ++r)
                    pe[ct][r] += tbl[ib + ct * 16 + r];
        }

        // lane-local max; rescale only when row max grew past defer threshold
        float lmax = pe[0][0];
        #pragma unroll
        for (int ct = 0; ct < 4; ++ct)
            #pragma unroll
            for (int r = 0; r < 4; ++r)
                lmax = fmaxf(lmax, pe[ct][r]);
        if (__any(lmax > mreg - cb + 8.f)) {
            float rm = fmaxf(lmax, __shfl_xor(lmax, 16));
            rm = fmaxf(rm, __shfl_xor(rm, 32));
            float mnew = fmaxf(mreg, rm + cb);
            float alpha = __expf(mreg - mnew);
            lreg *= alpha;
            #pragma unroll
            for (int dt = 0; dt < 4; ++dt)
                #pragma unroll
                for (int r = 0; r < 4; ++r)
                    o[dt][r] *= alpha;
            mreg = mnew;
        }
        const float madj = mreg - cb;
        float rs = 0.f;
        #pragma unroll
        for (int ct = 0; ct < 4; ++ct) {
            float p[4];
            #pragma unroll
            for (int r = 0; r < 4; ++r) {
                float pv = __expf(pe[ct][r] - madj);
                pv = ((const int*)&cm[ct])[r] ? pv : 0.f;
                p[r] = pv;
                rs += pv;
            }
            uint2v pk;
            pk[0] = cvt_pk_bf16(p[0], p[1]);
            pk[1] = cvt_pk_bf16(p[2], p[3]);
            *(uint2v*)&sP[w][lr][ct * 16 + lg * 4] = pk;
        }
        lreg += rs;

        // O^T += V^T * P^T
        #pragma unroll
        for (int kk = 0; kk < 2; ++kk) {
            short8 pf = *(const short8*)&sP[w][lr][kk * 32 + lg * 8];
            #pragma unroll
            for (int dt = 0; dt < 4; ++dt) {
                short8 vf = *(const short8*)&sV[(dt * 16 + lr) * 64 + ((kk * 32 + lg * 8) ^ sw8)];
                o[dt] = MFMA16(vf, pf, o[dt]);
            }
        }
        __syncthreads();
    }

    float lsum = lreg + __shfl_xor(lreg, 16);
    lsum += __shfl_xor(lsum, 32);
    const float inv = 1.0f / lsum;
    #pragma unroll
    for (int dt = 0; dt < 4; ++dt) {
        short4v ov;
        #pragma unroll
        for (int r = 0; r < 4; ++r) ov[r] = f2bf(o[dt][r] * inv);
        *(short4v*)(xout + (size_t)(b * 2048 + q0 + lr) * 1024 + h * 64 + dt * 16 + lg * 4) = ov;
    }
}

extern "C" void kernel_launch(void* const* d_in, const int* in_sizes, int n_in,
                              void* d_out, int out_size, void* d_ws, size_t ws_size,
                              hipStream_t stream) {
    const float* hidden = (const float*)d_in[0];
    const int* amask = (const int*)d_in[1];
    const float* w_qkv = (const float*)d_in[2];
    const float* rel_bias = (const float*)d_in[3];
    const float* w_o = (const float*)d_in[4];
    if (ws_size < 58720256) return;
    char* ws = (char*)d_ws;
    short* hidden_bf = (short*)(ws + 0);
    short* wqkv_bf   = (short*)(ws + 8388608);
    short* wo_bf     = (short*)(ws + 14680064);
    short* qkv       = (short*)(ws + 16777216);
    short* vt        = (short*)(ws + 41943040);
    short* xbuf      = (short*)(ws + 50331648);

    cast_f32_bf16<<<2048, 256, 0, stream>>>(hidden, hidden_bf, 524288);
    cast_f32_bf16<<<1536, 256, 0, stream>>>(w_qkv, wqkv_bf, 393216);
    cast_f32_bf16<<<512, 256, 0, stream>>>(w_o, wo_bf, 131072);
    gemm_bt<1><<<dim3(24, 32), 256, 0, stream>>>(hidden_bf, wqkv_bf, qkv, 4096, 3072, 1024);
    transpose_v<<<dim3(32, 32), 256, 0, stream>>>(qkv, vt);
    attn_kernel<<<dim3(32, 32), 256, 0, stream>>>(qkv, vt, amask, rel_bias, xbuf);
    gemm_bt<0><<<dim3(8, 32), 256, 0, stream>>>(xbuf, wo_bf, d_out, 4096, 1024, 1024);
}